// Round 4
// baseline (3079.894 us; speedup 1.0000x reference)
//
#include <hip/hip_runtime.h>

#define NN 100000
#define IN_CH 128
#define HID 32
#define OUT_CH 64
#define N_LAYERS 16
#define NB1 2048            // k_agg blocks (4 waves each -> 8192 waves)
#define RUNLEN 13           // nodes per wave: 8192*13 = 106496 >= NN
#define EPS_MSG 1e-7f
#define EPS_SM 1e-16f
#define EPS_BN 1e-5f

// ---------------- CSR build ----------------

__global__ void k_hist(const int* __restrict__ dst, int* __restrict__ counts, int E) {
    int i = blockIdx.x * 256 + threadIdx.x;
    if (i < E) atomicAdd(&counts[dst[i]], 1);
}

__global__ void k_scan1(const int* __restrict__ counts, int* __restrict__ rowptr,
                        int* __restrict__ bsum, int n) {
    __shared__ int sh[1024];
    int t = threadIdx.x;
    int i = blockIdx.x * 1024 + t;
    int v = (i < n) ? counts[i] : 0;
    sh[t] = v;
    __syncthreads();
    for (int off = 1; off < 1024; off <<= 1) {
        int tmp = (t >= off) ? sh[t - off] : 0;
        __syncthreads();
        sh[t] += tmp;
        __syncthreads();
    }
    if (i < n) rowptr[i] = sh[t] - v;   // exclusive within chunk
    if (t == 1023) bsum[blockIdx.x] = sh[1023];
}

__global__ void k_scan2(int* __restrict__ bsum, int nb) {
    if (threadIdx.x == 0 && blockIdx.x == 0) {
        int acc = 0;
        for (int b = 0; b < nb; b++) { int v = bsum[b]; bsum[b] = acc; acc += v; }
    }
}

__global__ void k_scan3(int* __restrict__ rowptr, int* __restrict__ cursor,
                        const int* __restrict__ bsum, int n, int E) {
    int i = blockIdx.x * 256 + threadIdx.x;
    if (i < n) {
        int r = rowptr[i] + bsum[i >> 10];
        rowptr[i] = r;
        cursor[i] = r;
    }
    if (i == 0) rowptr[n] = E;
}

__global__ void k_scatter(const int* __restrict__ src, const int* __restrict__ dst,
                          int* __restrict__ cursor, int* __restrict__ col, int E) {
    int i = blockIdx.x * 256 + threadIdx.x;
    if (i < E) {
        int d = dst[i];
        int p = atomicAdd(&cursor[d], 1);
        col[p] = src[i];
    }
}

// ---------------- input projection: h0 = x @ w0 + b0 ----------------

__global__ __launch_bounds__(256) void k0(const float* __restrict__ x,
                                          const float* __restrict__ w0,
                                          const float* __restrict__ b0,
                                          float* __restrict__ h) {
    __shared__ float ws[IN_CH * HID];   // 16 KB
    __shared__ float xs[8][IN_CH];      // 4 KB
    int tid = threadIdx.x, c = tid & 31, g = tid >> 5;
    for (int k = tid; k < IN_CH * HID; k += 256) ws[k] = w0[k];
    int d = blockIdx.x * 8 + g;
    float4 xv = ((const float4*)(x + (size_t)d * IN_CH))[c];
    ((float4*)xs[g])[c] = xv;
    __syncthreads();
    float acc = b0[c];
#pragma unroll 16
    for (int k = 0; k < IN_CH; k++) acc += xs[g][k] * ws[k * HID + c];
    h[(size_t)d * HID + c] = acc;
}

// ---------------- per-layer: softmax-agg + residual + lin1 + BN partials ----------------
// One node per FULL wave; run of RUNLEN contiguous nodes per wave. rowptr
// preloaded per run; up to 16 gather loads in flight (2 edges/load via the
// two 32-lane halves); lin1 entirely in registers (w1reg + shfl broadcast).
// __launch_bounds__(256,4): allow up to 128 VGPRs so the compiler does NOT
// squeeze to 32 regs and serialize the gather loads (round-3 failure mode).

__global__ __launch_bounds__(256, 4) void k_agg(const float* __restrict__ h,
                                                const int* __restrict__ rowptr,
                                                const int* __restrict__ col,
                                                const float* __restrict__ w1,
                                                const float* __restrict__ b1,
                                                float* __restrict__ z,
                                                float* __restrict__ zsum,
                                                int layer) {
    int tid = threadIdx.x;
    int lane = tid & 63;
    int wslot = tid >> 6;                  // wave within block (0..3)
    int wid = blockIdx.x * 4 + wslot;      // global wave id
    int c = lane & 31;                     // channel
    int parity = lane >> 5;                // which half handles odd/even edge slots

    // per-lane lin1 weights: lane j holds w1[k][j] for all k (32 VGPRs)
    float w1reg[32];
#pragma unroll
    for (int k = 0; k < 32; k++) w1reg[k] = w1[layer * 2048 + k * 64 + lane];
    float b1reg = b1[layer * 64 + lane];

    float s_acc = 0.f, q_acc = 0.f;

    int base = wid * RUNLEN;
    // preload rowptr for the whole run (coalesced, once)
    int rpidx = base + (lane <= RUNLEN ? lane : RUNLEN);
    if (rpidx > NN) rpidx = NN;
    int rp = rowptr[rpidx];

    for (int i = 0; i < RUNLEN; i++) {
        int d = base + i;
        if (d >= NN) break;                          // wave-uniform
        int r0 = __shfl(rp, i, 64);
        int r1 = __shfl(rp, i + 1, 64);
        float hres = h[(size_t)d * HID + c];         // residual (issue early)
        float den = 0.f, num = 0.f;
        for (int e0 = r0; e0 < r1; e0 += 32) {
            int colw = col[e0 + c];                  // 32-edge window (both halves)
            int nb = r1 - e0; if (nb > 32) nb = 32;  // wave-uniform
            int nsteps = (nb + 1) >> 1;              // 2 edges per step
            float vv[16];
            // issue ALL gathers for this window before any exp
#pragma unroll
            for (int j = 0; j < 16; j++) {
                if (j < nsteps) {                    // uniform branch: no waste
                    int s = __shfl(colw, 2 * j + parity, 32);
                    vv[j] = h[(size_t)s * HID + c];
                }
            }
#pragma unroll
            for (int j = 0; j < 16; j++) {
                if (j < nsteps) {
                    float v = fmaxf(vv[j], 0.f) + EPS_MSG;
                    float ev = __expf(v);            // bounded: no max-subtraction
                    bool ok = (2 * j + parity) < nb;
                    den += ok ? ev : 0.f;
                    num += ok ? ev * v : 0.f;
                }
            }
        }
        // combine the two halves (each did half the edges)
        den += __shfl_xor(den, 32, 64);
        num += __shfl_xor(num, 32, 64);
        float out = num / (den + EPS_SM) + hres;     // same value in both halves
        // lin1: z_lane = b1[lane] + sum_k out_k * w1[k][lane]
        float zv = b1reg;
#pragma unroll
        for (int k = 0; k < 32; k++)
            zv = fmaf(__shfl(out, k, 64), w1reg[k], zv);
        z[(size_t)d * 64 + lane] = zv;
        s_acc += zv; q_acc += zv * zv;
    }

    // block reduce BN partials; slotted atomics (16 slots/channel) to avoid
    // 2048-way same-address contention
    __shared__ float red[256];
    int slot = blockIdx.x & 15;
    red[tid] = s_acc; __syncthreads();
    if (tid < 64) {
        float a = red[tid] + red[tid + 64] + red[tid + 128] + red[tid + 192];
        atomicAdd(&zsum[layer * 2048 + tid * 16 + slot], a);
    }
    __syncthreads();
    red[tid] = q_acc; __syncthreads();
    if (tid < 64) {
        float a = red[tid] + red[tid + 64] + red[tid + 128] + red[tid + 192];
        atomicAdd(&zsum[layer * 2048 + (64 + tid) * 16 + slot], a);
    }
}

// ---------------- BN apply + relu + lin2 + relu (BN stats finalized in-block) ----------------

__global__ __launch_bounds__(256) void k_bn2(const float* __restrict__ z,
                                             const float* __restrict__ zsum,
                                             const float* __restrict__ gamma,
                                             const float* __restrict__ beta,
                                             const float* __restrict__ w2,
                                             const float* __restrict__ b2,
                                             float* __restrict__ hout,
                                             int layer) {
    __shared__ float w2s[64 * HID];   // 8 KB
    __shared__ float zs[8][64];
    __shared__ float scs[64], shs[64];
    int tid = threadIdx.x, c = tid & 31, g = tid >> 5;
    for (int k = tid; k < 64 * HID; k += 256) w2s[k] = w2[layer * (64 * HID) + k];
    if (tid < 64) {
        float S = 0.f, Q = 0.f;
#pragma unroll
        for (int s2 = 0; s2 < 16; s2++) {
            S += zsum[layer * 2048 + tid * 16 + s2];
            Q += zsum[layer * 2048 + (64 + tid) * 16 + s2];
        }
        float mean = S * (1.0f / NN);
        float var = Q * (1.0f / NN) - mean * mean;
        float sc = gamma[layer * 64 + tid] * rsqrtf(var + EPS_BN);
        scs[tid] = sc;
        shs[tid] = beta[layer * 64 + tid] - mean * sc;
    }
    __syncthreads();
    int d = blockIdx.x * 8 + g;
    float z0 = z[(size_t)d * 64 + c] * scs[c] + shs[c];
    float z1 = z[(size_t)d * 64 + 32 + c] * scs[c + 32] + shs[c + 32];
    zs[g][c] = fmaxf(z0, 0.f);
    zs[g][c + 32] = fmaxf(z1, 0.f);
    __syncthreads();
    float acc = b2[layer * HID + c];
#pragma unroll
    for (int k = 0; k < 64; k++) acc += zs[g][k] * w2s[k * HID + c];
    hout[(size_t)d * HID + c] = fmaxf(acc, 0.f);
}

// ---------------- output projection: out = h @ w16 + b16 ----------------

__global__ __launch_bounds__(256) void k_final(const float* __restrict__ h,
                                               const float* __restrict__ w16,
                                               const float* __restrict__ b16,
                                               float* __restrict__ out) {
    __shared__ float ws[HID * OUT_CH];   // 8 KB
    __shared__ float hs[8][HID];
    int tid = threadIdx.x, c = tid & 31, g = tid >> 5;
    for (int k = tid; k < HID * OUT_CH; k += 256) ws[k] = w16[k];
    int d = blockIdx.x * 8 + g;
    hs[g][c] = h[(size_t)d * HID + c];
    __syncthreads();
    float o0 = b16[c], o1 = b16[c + 32];
#pragma unroll
    for (int k = 0; k < HID; k++) {
        float hv = hs[g][k];
        o0 += hv * ws[k * OUT_CH + c];
        o1 += hv * ws[k * OUT_CH + c + 32];
    }
    out[(size_t)d * OUT_CH + c] = o0;
    out[(size_t)d * OUT_CH + 32 + c] = o1;
}

// ---------------- host ----------------

extern "C" void kernel_launch(void* const* d_in, const int* in_sizes, int n_in,
                              void* d_out, int out_size, void* d_ws, size_t ws_size,
                              hipStream_t stream) {
    const float* x      = (const float*)d_in[0];
    const int*   ei     = (const int*)d_in[1];
    const float* w0     = (const float*)d_in[2];
    const float* b0     = (const float*)d_in[3];
    const float* lin1_w = (const float*)d_in[4];
    const float* lin1_b = (const float*)d_in[5];
    const float* gamma  = (const float*)d_in[6];
    const float* beta   = (const float*)d_in[7];
    const float* lin2_w = (const float*)d_in[8];
    const float* lin2_b = (const float*)d_in[9];
    const float* w16    = (const float*)d_in[10];
    const float* b16    = (const float*)d_in[11];
    float* out = (float*)d_out;

    const int E = in_sizes[1] / 2;
    const int* src = ei;
    const int* dst = ei + E;

    // workspace carve-up (all 256B-aligned)
    char* p = (char*)d_ws;
    auto alloc = [&](size_t bytes) {
        char* q = p;
        p += (bytes + 255) & ~(size_t)255;
        return q;
    };
    float* hA       = (float*)alloc((size_t)NN * HID * 4);
    float* hB       = (float*)alloc((size_t)NN * HID * 4);
    float* z        = (float*)alloc((size_t)NN * 64 * 4);
    int*   rowptr   = (int*)alloc((size_t)(NN + 1) * 4);
    int*   cursor   = (int*)alloc((size_t)NN * 4);
    int*   counts   = (int*)alloc((size_t)NN * 4);
    int*   col      = (int*)alloc((size_t)(E + 32) * 4);   // +32 pad for windowed reads
    int*   bsum     = (int*)alloc(1024 * 4);
    float* zsum     = (float*)alloc((size_t)N_LAYERS * 2048 * 4);  // [L][128ch][16 slots]
    (void)ws_size; (void)n_in; (void)out_size;

    // --- zero accumulators + CSR build (once per call; reused by all layers) ---
    hipMemsetAsync(counts, 0, (size_t)NN * 4, stream);
    hipMemsetAsync(zsum, 0, (size_t)N_LAYERS * 2048 * 4, stream);
    hipMemsetAsync(col + E, 0, 32 * 4, stream);   // pad entries -> node 0 (safe loads)
    int egrid = (E + 255) / 256;
    k_hist<<<egrid, 256, 0, stream>>>(dst, counts, E);
    int b1g = (NN + 1023) / 1024;
    k_scan1<<<b1g, 1024, 0, stream>>>(counts, rowptr, bsum, NN);
    k_scan2<<<1, 1, 0, stream>>>(bsum, b1g);
    k_scan3<<<(NN + 255) / 256, 256, 0, stream>>>(rowptr, cursor, bsum, NN, E);
    k_scatter<<<egrid, 256, 0, stream>>>(src, dst, cursor, col, E);

    // --- input projection ---
    k0<<<NN / 8, 256, 0, stream>>>(x, w0, b0, hA);

    // --- 16 layers ---
    float* hin = hA;
    float* hout = hB;
    for (int i = 0; i < N_LAYERS; i++) {
        k_agg<<<NB1, 256, 0, stream>>>(hin, rowptr, col, lin1_w, lin1_b, z, zsum, i);
        k_bn2<<<NN / 8, 256, 0, stream>>>(z, zsum, gamma, beta, lin2_w, lin2_b, hout, i);
        float* t = hin; hin = hout; hout = t;
    }

    // --- output projection ---
    k_final<<<NN / 8, 256, 0, stream>>>(hin, w16, b16, out);
}

// Round 5
// 2914.276 us; speedup vs baseline: 1.0568x; 1.0568x over previous
//
#include <hip/hip_runtime.h>
#include <hip/hip_fp16.h>

#define NN 100000
#define IN_CH 128
#define HID 32
#define OUT_CH 64
#define N_LAYERS 16
#define NB1 2048            // k_agg blocks (4 waves each)
#define EPS_MSG 1e-7f
#define EPS_SM 1e-16f
#define EPS_BN 1e-5f

// ---------------- CSR build ----------------

__global__ void k_hist(const int* __restrict__ dst, int* __restrict__ counts, int E) {
    int i = blockIdx.x * 256 + threadIdx.x;
    if (i < E) atomicAdd(&counts[dst[i]], 1);
}

__global__ void k_scan1(const int* __restrict__ counts, int* __restrict__ rowptr,
                        int* __restrict__ bsum, int n) {
    __shared__ int sh[1024];
    int t = threadIdx.x;
    int i = blockIdx.x * 1024 + t;
    int v = (i < n) ? counts[i] : 0;
    sh[t] = v;
    __syncthreads();
    for (int off = 1; off < 1024; off <<= 1) {
        int tmp = (t >= off) ? sh[t - off] : 0;
        __syncthreads();
        sh[t] += tmp;
        __syncthreads();
    }
    if (i < n) rowptr[i] = sh[t] - v;   // exclusive within chunk
    if (t == 1023) bsum[blockIdx.x] = sh[1023];
}

__global__ void k_scan2(int* __restrict__ bsum, int nb) {
    if (threadIdx.x == 0 && blockIdx.x == 0) {
        int acc = 0;
        for (int b = 0; b < nb; b++) { int v = bsum[b]; bsum[b] = acc; acc += v; }
    }
}

__global__ void k_scan3(int* __restrict__ rowptr, int* __restrict__ cursor,
                        const int* __restrict__ bsum, int n, int E) {
    int i = blockIdx.x * 256 + threadIdx.x;
    if (i < n) {
        int r = rowptr[i] + bsum[i >> 10];
        rowptr[i] = r;
        cursor[i] = r;
    }
    if (i == 0) rowptr[n] = E;
}

__global__ void k_scatter(const int* __restrict__ src, const int* __restrict__ dst,
                          int* __restrict__ cursor, int* __restrict__ col, int E) {
    int i = blockIdx.x * 256 + threadIdx.x;
    if (i < E) {
        int d = dst[i];
        int p = atomicAdd(&cursor[d], 1);
        col[p] = src[i];
    }
}

// ---------------- input projection: h0 = x @ w0 + b0 (+ fp16 message precompute) ----------------

__global__ __launch_bounds__(256) void k0(const float* __restrict__ x,
                                          const float* __restrict__ w0,
                                          const float* __restrict__ b0,
                                          float* __restrict__ h,
                                          __half* __restrict__ m16) {
    __shared__ float ws[IN_CH * HID];   // 16 KB
    __shared__ float xs[8][IN_CH];      // 4 KB
    int tid = threadIdx.x, c = tid & 31, g = tid >> 5;
    for (int k = tid; k < IN_CH * HID; k += 256) ws[k] = w0[k];
    int d = blockIdx.x * 8 + g;
    float4 xv = ((const float4*)(x + (size_t)d * IN_CH))[c];
    ((float4*)xs[g])[c] = xv;
    __syncthreads();
    float acc = b0[c];
#pragma unroll 16
    for (int k = 0; k < IN_CH; k++) acc += xs[g][k] * ws[k * HID + c];
    h[(size_t)d * HID + c] = acc;
    m16[(size_t)d * HID + c] = __float2half(fmaxf(acc, 0.f) + EPS_MSG);
}

// ---------------- per-layer: softmax-agg + residual + lin1 + BN partials ----------------
// Half-wave (32 lanes = 32 channels) per node, barrier-free hot loop.
// Gathers read the fp16 precomputed message m16 (64 B/edge = 1 cache line,
// vs 128 B fp32): halves per-CU miss-line traffic, the round-5 theory.

__global__ __launch_bounds__(256, 4) void k_agg(const float* __restrict__ h,
                                                const __half* __restrict__ m16,
                                                const int* __restrict__ rowptr,
                                                const int* __restrict__ col,
                                                const float* __restrict__ w1,
                                                const float* __restrict__ b1,
                                                float* __restrict__ z,
                                                float* __restrict__ zsum,
                                                int layer) {
    __shared__ float w1s[HID * 64];   // 8 KB
    __shared__ float b1s[64];
    __shared__ float red[256];
    int tid = threadIdx.x, c = tid & 31;
    int half = (tid >> 5) & 1;                       // node slot within wave
    int wid = (blockIdx.x * 256 + tid) >> 6;         // global wave id
    for (int k = tid; k < HID * 64; k += 256) w1s[k] = w1[layer * (HID * 64) + k];
    if (tid < 64) b1s[tid] = b1[layer * 64 + tid];
    float s0 = 0.f, s1 = 0.f, q0 = 0.f, q1 = 0.f;
    __syncthreads();

    const int stride = NB1 * 4 * 2;                  // total waves * 2 nodes
    for (int d = wid * 2 + half; d < NN; d += stride) {
        int r0 = rowptr[d], r1 = rowptr[d + 1];
        float hres = h[(size_t)d * HID + c];         // residual (issue early)
        float den = 0.f, num = 0.f;
        for (int e0 = r0; e0 < r1; e0 += 32) {
            int colv = col[e0 + c];                  // 32 edge srcs, one coalesced load
            int nb = r1 - e0; if (nb > 32) nb = 32;
            for (int j0 = 0; j0 < nb; j0 += 8) {
                float vv[8];
#pragma unroll
                for (int j = 0; j < 8; j++) {
                    int s = __shfl(colv, j0 + j, 32);
                    vv[j] = __half2float(m16[(size_t)s * HID + c]);  // unconditional; col padded
                }
#pragma unroll
                for (int j = 0; j < 8; j++) {
                    float ev = __expf(vv[j]);        // bounded: no max-subtraction needed
                    bool ok = (j0 + j) < nb;
                    den += ok ? ev : 0.f;
                    num += ok ? ev * vv[j] : 0.f;
                }
            }
        }
        float out = num / (den + EPS_SM) + hres;
        // lin1 via shuffle within the 32-lane half-wave
        float z0 = b1s[c], z1 = b1s[c + 32];
#pragma unroll
        for (int k = 0; k < HID; k++) {
            float o = __shfl(out, k, 32);
            z0 += o * w1s[k * 64 + c];
            z1 += o * w1s[k * 64 + c + 32];
        }
        z[(size_t)d * 64 + c] = z0;
        z[(size_t)d * 64 + 32 + c] = z1;
        s0 += z0; s1 += z1; q0 += z0 * z0; q1 += z1 * z1;
    }

    // block reduce BN partials; slotted atomics (16 slots/channel) to avoid
    // 2048-way same-address contention tails
    float* acc = zsum + layer * 2048;
    int slot = blockIdx.x & 15;
    red[tid] = s0; __syncthreads();
    if (tid < 32) { float a = 0; for (int g2 = 0; g2 < 8; g2++) a += red[g2 * 32 + tid]; atomicAdd(&acc[tid * 16 + slot], a); }
    __syncthreads();
    red[tid] = s1; __syncthreads();
    if (tid < 32) { float a = 0; for (int g2 = 0; g2 < 8; g2++) a += red[g2 * 32 + tid]; atomicAdd(&acc[(32 + tid) * 16 + slot], a); }
    __syncthreads();
    red[tid] = q0; __syncthreads();
    if (tid < 32) { float a = 0; for (int g2 = 0; g2 < 8; g2++) a += red[g2 * 32 + tid]; atomicAdd(&acc[(64 + tid) * 16 + slot], a); }
    __syncthreads();
    red[tid] = q1; __syncthreads();
    if (tid < 32) { float a = 0; for (int g2 = 0; g2 < 8; g2++) a += red[g2 * 32 + tid]; atomicAdd(&acc[(96 + tid) * 16 + slot], a); }
}

// ---------------- BN apply + relu + lin2 + relu (+ fp16 message precompute) ----------------

__global__ __launch_bounds__(256) void k_bn2(const float* __restrict__ z,
                                             const float* __restrict__ zsum,
                                             const float* __restrict__ gamma,
                                             const float* __restrict__ beta,
                                             const float* __restrict__ w2,
                                             const float* __restrict__ b2,
                                             float* __restrict__ hout,
                                             __half* __restrict__ m16,
                                             int layer) {
    __shared__ float w2s[64 * HID];   // 8 KB
    __shared__ float zs[8][64];
    __shared__ float scs[64], shs[64];
    int tid = threadIdx.x, c = tid & 31, g = tid >> 5;
    for (int k = tid; k < 64 * HID; k += 256) w2s[k] = w2[layer * (64 * HID) + k];
    if (tid < 64) {
        float S = 0.f, Q = 0.f;
#pragma unroll
        for (int s2 = 0; s2 < 16; s2++) {
            S += zsum[layer * 2048 + tid * 16 + s2];
            Q += zsum[layer * 2048 + (64 + tid) * 16 + s2];
        }
        float mean = S * (1.0f / NN);
        float var = Q * (1.0f / NN) - mean * mean;
        float sc = gamma[layer * 64 + tid] * rsqrtf(var + EPS_BN);
        scs[tid] = sc;
        shs[tid] = beta[layer * 64 + tid] - mean * sc;
    }
    __syncthreads();
    int d = blockIdx.x * 8 + g;
    float z0 = z[(size_t)d * 64 + c] * scs[c] + shs[c];
    float z1 = z[(size_t)d * 64 + 32 + c] * scs[c + 32] + shs[c + 32];
    zs[g][c] = fmaxf(z0, 0.f);
    zs[g][c + 32] = fmaxf(z1, 0.f);
    __syncthreads();
    float acc = b2[layer * HID + c];
#pragma unroll
    for (int k = 0; k < 64; k++) acc += zs[g][k] * w2s[k * HID + c];
    float r = fmaxf(acc, 0.f);
    hout[(size_t)d * HID + c] = r;
    m16[(size_t)d * HID + c] = __float2half(r + EPS_MSG);   // relu(h)+eps, h>=0 here
}

// ---------------- output projection: out = h @ w16 + b16 ----------------

__global__ __launch_bounds__(256) void k_final(const float* __restrict__ h,
                                               const float* __restrict__ w16,
                                               const float* __restrict__ b16,
                                               float* __restrict__ out) {
    __shared__ float ws[HID * OUT_CH];   // 8 KB
    __shared__ float hs[8][HID];
    int tid = threadIdx.x, c = tid & 31, g = tid >> 5;
    for (int k = tid; k < HID * OUT_CH; k += 256) ws[k] = w16[k];
    int d = blockIdx.x * 8 + g;
    hs[g][c] = h[(size_t)d * HID + c];
    __syncthreads();
    float o0 = b16[c], o1 = b16[c + 32];
#pragma unroll
    for (int k = 0; k < HID; k++) {
        float hv = hs[g][k];
        o0 += hv * ws[k * OUT_CH + c];
        o1 += hv * ws[k * OUT_CH + c + 32];
    }
    out[(size_t)d * OUT_CH + c] = o0;
    out[(size_t)d * OUT_CH + 32 + c] = o1;
}

// ---------------- host ----------------

extern "C" void kernel_launch(void* const* d_in, const int* in_sizes, int n_in,
                              void* d_out, int out_size, void* d_ws, size_t ws_size,
                              hipStream_t stream) {
    const float* x      = (const float*)d_in[0];
    const int*   ei     = (const int*)d_in[1];
    const float* w0     = (const float*)d_in[2];
    const float* b0     = (const float*)d_in[3];
    const float* lin1_w = (const float*)d_in[4];
    const float* lin1_b = (const float*)d_in[5];
    const float* gamma  = (const float*)d_in[6];
    const float* beta   = (const float*)d_in[7];
    const float* lin2_w = (const float*)d_in[8];
    const float* lin2_b = (const float*)d_in[9];
    const float* w16    = (const float*)d_in[10];
    const float* b16    = (const float*)d_in[11];
    float* out = (float*)d_out;

    const int E = in_sizes[1] / 2;
    const int* src = ei;
    const int* dst = ei + E;

    // workspace carve-up (all 256B-aligned)
    char* p = (char*)d_ws;
    auto alloc = [&](size_t bytes) {
        char* q = p;
        p += (bytes + 255) & ~(size_t)255;
        return q;
    };
    float*  hA     = (float*)alloc((size_t)NN * HID * 4);
    float*  hB     = (float*)alloc((size_t)NN * HID * 4);
    __half* m16    = (__half*)alloc((size_t)NN * HID * 2);
    float*  z      = (float*)alloc((size_t)NN * 64 * 4);
    int*    rowptr = (int*)alloc((size_t)(NN + 1) * 4);
    int*    cursor = (int*)alloc((size_t)NN * 4);
    int*    counts = (int*)alloc((size_t)NN * 4);
    int*    col    = (int*)alloc((size_t)(E + 32) * 4);   // +32 pad for windowed reads
    int*    bsum   = (int*)alloc(1024 * 4);
    float*  zsum   = (float*)alloc((size_t)N_LAYERS * 2048 * 4);  // [L][128ch][16 slots]
    (void)ws_size; (void)n_in; (void)out_size;

    // --- zero accumulators + CSR build (once per call; reused by all layers) ---
    hipMemsetAsync(counts, 0, (size_t)NN * 4, stream);
    hipMemsetAsync(zsum, 0, (size_t)N_LAYERS * 2048 * 4, stream);
    hipMemsetAsync(col + E, 0, 32 * 4, stream);   // pad entries -> node 0 (safe loads)
    int egrid = (E + 255) / 256;
    k_hist<<<egrid, 256, 0, stream>>>(dst, counts, E);
    int b1g = (NN + 1023) / 1024;
    k_scan1<<<b1g, 1024, 0, stream>>>(counts, rowptr, bsum, NN);
    k_scan2<<<1, 1, 0, stream>>>(bsum, b1g);
    k_scan3<<<(NN + 255) / 256, 256, 0, stream>>>(rowptr, cursor, bsum, NN, E);
    k_scatter<<<egrid, 256, 0, stream>>>(src, dst, cursor, col, E);

    // --- input projection (+ message precompute) ---
    k0<<<NN / 8, 256, 0, stream>>>(x, w0, b0, hA, m16);

    // --- 16 layers ---
    float* hin = hA;
    float* hout = hB;
    for (int i = 0; i < N_LAYERS; i++) {
        k_agg<<<NB1, 256, 0, stream>>>(hin, m16, rowptr, col, lin1_w, lin1_b, z, zsum, i);
        k_bn2<<<NN / 8, 256, 0, stream>>>(z, zsum, gamma, beta, lin2_w, lin2_b, hout, m16, i);
        float* t = hin; hin = hout; hout = t;
    }

    // --- output projection ---
    k_final<<<NN / 8, 256, 0, stream>>>(hin, w16, b16, out);
}